// Round 1
// baseline (148.431 us; speedup 1.0000x reference)
//
#include <hip/hip_runtime.h>
#include <hip/hip_bf16.h>
#include <stdint.h>

typedef __attribute__((ext_vector_type(8))) short short8;
typedef __attribute__((ext_vector_type(4))) float f32x4;

#define DD 512
#define TT 64   // tokens per block
#define TN 4096 // T
#define NB 8    // B

__device__ __forceinline__ unsigned short f2bf(float f){
  uint32_t u = __float_as_uint(f);
  u += 0x7FFFu + ((u >> 16) & 1u);
  return (unsigned short)(u >> 16);
}
__device__ __forceinline__ float bf2f(unsigned short h){
  return __uint_as_float(((uint32_t)h) << 16);
}

// ---------------- prep kernels (tiny) ----------------

// spk[b][s*512+d] = relu(speaker_emb[b]·We[s*512+d] + be) + spk_pos[s*512+d]
__global__ void prep_spk(const float* __restrict__ se, const float* __restrict__ We,
                         const float* __restrict__ be, const float* __restrict__ spos,
                         float* __restrict__ spk){
  int idx = blockIdx.x * 256 + threadIdx.x;     // 16384
  int b = idx & 7, od = idx >> 3;
  const float* wr = We + (size_t)od * DD;
  const float* sb = se + b * DD;
  float acc = be[od];
  for (int i = 0; i < DD; i++) acc += sb[i] * wr[i];
  acc = fmaxf(acc, 0.f) + spos[od];
  spk[b * 2048 + od] = acc;
}

// k[b][s][hd], v[b][s][hd]
__global__ void prep_kv(const float* __restrict__ spk, const float* __restrict__ Wk,
                        const float* __restrict__ bk, const float* __restrict__ Wv,
                        const float* __restrict__ bv, float* __restrict__ kb,
                        float* __restrict__ vb){
  int idx = blockIdx.x * 256 + threadIdx.x;     // 16384
  int hd = idx >> 5; int r = idx & 31; int b = r >> 2, s = r & 3;
  const float* sp = spk + (b * 4 + s) * DD;
  const float* wkr = Wk + (size_t)hd * DD;
  const float* wvr = Wv + (size_t)hd * DD;
  float ak = bk[hd], av = bv[hd];
  for (int i = 0; i < DD; i++){ float x = sp[i]; ak += x * wkr[i]; av += x * wvr[i]; }
  kb[(b * 4 + s) * DD + hd] = ak;
  vb[(b * 4 + s) * DD + hd] = av;
}

// m[b][j=h*4+s][d] = sum_dh Wq[h*64+dh][d] * k[b,s,h*64+dh]   (bf16)
// uT[b][d][j]      = sum_dh v[b,s,h*64+dh] * Wo[d][h*64+dh]   (bf16)
// c[b][j]          = sum_dh bq[h*64+dh]    * k[b,s,h*64+dh]
// wg1B             = bf16(Wg1)
__global__ void prep_mu(const float* __restrict__ kb, const float* __restrict__ vb,
                        const float* __restrict__ Wq, const float* __restrict__ bq,
                        const float* __restrict__ Wo, const float* __restrict__ Wg1,
                        unsigned short* __restrict__ mB, unsigned short* __restrict__ uT,
                        float* __restrict__ cArr, unsigned short* __restrict__ wg1B){
  int idx = blockIdx.x * 256 + threadIdx.x;     // 327936 total
  if (idx < 131072){
    int d = idx & 511; int j = (idx >> 9) & 31; int b = idx >> 14;
    int h = j >> 2, s = j & 3;
    const float* kr = kb + (b * 4 + s) * DD + h * 64;
    const float* wq = Wq + (size_t)(h * 64) * DD + d;
    float acc = 0.f;
    for (int dh = 0; dh < 64; dh++) acc += wq[(size_t)dh * DD] * kr[dh];
    mB[idx] = f2bf(acc);
  } else if (idx < 262144){
    int t = idx - 131072;
    int j = t & 31; int d = (t >> 5) & 511; int b = t >> 14;
    int h = j >> 2, s = j & 3;
    const float* vr = vb + (b * 4 + s) * DD + h * 64;
    const float* wo = Wo + (size_t)d * DD + h * 64;
    float acc = 0.f;
    for (int dh = 0; dh < 64; dh++) acc += vr[dh] * wo[dh];
    uT[b * 16384 + d * 32 + j] = f2bf(acc);
  } else if (idx < 327680){
    int t = idx - 262144;
    wg1B[t] = f2bf(Wg1[t]);
  } else if (idx < 327936){
    int t = idx - 327680; int j = t & 31, b = t >> 5;
    int h = j >> 2, s = j & 3;
    const float* kr = kb + (b * 4 + s) * DD + h * 64;
    const float* bqp = bq + h * 64;
    float acc = 0.f;
    for (int dh = 0; dh < 64; dh++) acc += bqp[dh] * kr[dh];
    cArr[b * 32 + j] = acc;
  }
}

// ---------------- main fused kernel ----------------
// 64 tokens/block, 4 waves; wave w owns rows w*16..w*16+15.
// LDS: Xb (x bf16, swizzled), Lb (gate-LN(x) bf16, later y bf16), Wl (softmax weights).

__global__ __launch_bounds__(256) void fused_main(
    const float* __restrict__ xin,
    const float* __restrict__ glng, const float* __restrict__ glnb,
    const float* __restrict__ bg1v, const float* __restrict__ wg2v, const float* __restrict__ bg2v,
    const float* __restrict__ bov,  const float* __restrict__ lng,  const float* __restrict__ lnb,
    const unsigned short* __restrict__ mB,
    const unsigned short* __restrict__ uTB,
    const float* __restrict__ cArr,
    const unsigned short* __restrict__ wg1B,
    float* __restrict__ outF, float* __restrict__ outAW, float* __restrict__ outG)
{
  __shared__ __align__(16) unsigned short Xb[TT * DD];
  __shared__ __align__(16) unsigned short Lb[TT * DD];
  __shared__ __align__(16) unsigned short Wl[TT * 32];
  __shared__ float gbuf[TT];
  __shared__ float s2mu[TT], s2rs[TT];

  const int tid  = threadIdx.x;
  const int lane = tid & 63;
  const int wid  = tid >> 6;
  const int m0   = wid << 4;
  const int r16  = lane & 15;
  const int kg   = lane >> 4;
  const int bb   = blockIdx.x >> 6;           // batch
  const int t0   = (blockIdx.x & 63) << 6;    // token tile base
  const size_t rowbase = (size_t)bb * TN + t0;

  // ---- Phase 0: load X, gate-LN stats (fp32-exact), write Xb + Lb (bf16) ----
  const int c0 = lane << 3;   // this lane's 8 columns
  float ga[8], gb8[8];
  {
    float4 g0 = *(const float4*)(glng + c0);
    float4 g1 = *(const float4*)(glng + c0 + 4);
    float4 b0 = *(const float4*)(glnb + c0);
    float4 b1 = *(const float4*)(glnb + c0 + 4);
    ga[0]=g0.x; ga[1]=g0.y; ga[2]=g0.z; ga[3]=g0.w;
    ga[4]=g1.x; ga[5]=g1.y; ga[6]=g1.z; ga[7]=g1.w;
    gb8[0]=b0.x; gb8[1]=b0.y; gb8[2]=b0.z; gb8[3]=b0.w;
    gb8[4]=b1.x; gb8[5]=b1.y; gb8[6]=b1.z; gb8[7]=b1.w;
  }
  for (int rr = 0; rr < 16; rr++){
    const int r = m0 + rr;
    const float* rp = xin + (rowbase + r) * DD + c0;
    float4 v0 = *(const float4*)rp;
    float4 v1 = *(const float4*)(rp + 4);
    float xv[8] = {v0.x, v0.y, v0.z, v0.w, v1.x, v1.y, v1.z, v1.w};
    float s = 0.f, q = 0.f;
#pragma unroll
    for (int j = 0; j < 8; j++){ s += xv[j]; q += xv[j] * xv[j]; }
#pragma unroll
    for (int off = 1; off < 64; off <<= 1){
      s += __shfl_xor(s, off);
      q += __shfl_xor(q, off);
    }
    const float mu = s * (1.f / DD);
    const float rs = rsqrtf(q * (1.f / DD) - mu * mu + 1e-5f);
    short8 xvv, lvv;
#pragma unroll
    for (int j = 0; j < 8; j++){
      xvv[j] = (short)f2bf(xv[j]);
      lvv[j] = (short)f2bf((xv[j] - mu) * rs * ga[j] + gb8[j]);
    }
    const int ci = c0 ^ ((r & 7) << 3);
    *(short8*)&Xb[r * DD + ci] = xvv;
    *(short8*)&Lb[r * DD + ci] = lvv;
  }
  __syncthreads();

  // ---- Phase 1: scores S(64x32) = Xb · m^T, softmax over s (groups of 4) ----
  f32x4 sa0 = {0.f,0.f,0.f,0.f}, sa1 = {0.f,0.f,0.f,0.f};
  {
    const unsigned short* mb = mB + (size_t)bb * 32 * DD;
    const int ar = m0 + r16;
#pragma unroll
    for (int kt = 0; kt < 16; kt++){
      const int kc = kt * 32 + kg * 8;
      short8 a  = *(const short8*)&Xb[ar * DD + (kc ^ ((ar & 7) << 3))];
      short8 b0 = *(const short8*)&mb[r16 * DD + kc];
      short8 b1 = *(const short8*)&mb[(r16 + 16) * DD + kc];
      sa0 = __builtin_amdgcn_mfma_f32_16x16x32_bf16(a, b0, sa0, 0, 0, 0);
      sa1 = __builtin_amdgcn_mfma_f32_16x16x32_bf16(a, b1, sa1, 0, 0, 0);
    }
  }
  {
    const float c0v = cArr[bb * 32 + r16];
    const float c1v = cArr[bb * 32 + r16 + 16];
#pragma unroll
    for (int r = 0; r < 4; r++){
      float s0 = (sa0[r] + c0v) * 0.125f;
      float s1 = (sa1[r] + c1v) * 0.125f;
      float mx0 = fmaxf(s0, __shfl_xor(s0, 1)); mx0 = fmaxf(mx0, __shfl_xor(mx0, 2));
      float mx1 = fmaxf(s1, __shfl_xor(s1, 1)); mx1 = fmaxf(mx1, __shfl_xor(mx1, 2));
      float e0 = __expf(s0 - mx0), e1 = __expf(s1 - mx1);
      float d0 = e0; d0 += __shfl_xor(d0, 1); d0 += __shfl_xor(d0, 2);
      float d1 = e1; d1 += __shfl_xor(d1, 1); d1 += __shfl_xor(d1, 2);
      float w0 = e0 / d0, w1 = e1 / d1;
      float t = w0 + w1; t += __shfl_xor(t, 4); t += __shfl_xor(t, 8); t *= 0.125f;
      const int rw = m0 + kg * 4 + r;
      if ((lane & 12) == 0) outAW[(rowbase + rw) * 4 + (lane & 3)] = t;
      Wl[rw * 32 + r16]      = f2bf(w0);
      Wl[rw * 32 + r16 + 16] = f2bf(w1);
    }
  }
  __syncthreads();

  // ---- Phase 2: gate GEMM G(64x128) = Lb · Wg1^T, relu, ·Wg2, sigmoid ----
  {
    f32x4 gacc[8];
#pragma unroll
    for (int nt = 0; nt < 8; nt++){ f32x4 z = {0.f,0.f,0.f,0.f}; gacc[nt] = z; }
    const int ar = m0 + r16;
#pragma unroll
    for (int kt = 0; kt < 16; kt++){
      const int kc = kt * 32 + kg * 8;
      short8 a = *(const short8*)&Lb[ar * DD + (kc ^ ((ar & 7) << 3))];
#pragma unroll
      for (int nt = 0; nt < 8; nt++){
        short8 bf = *(const short8*)&wg1B[(nt * 16 + r16) * DD + kc];
        gacc[nt] = __builtin_amdgcn_mfma_f32_16x16x32_bf16(a, bf, gacc[nt], 0, 0, 0);
      }
    }
    float part[4] = {0.f, 0.f, 0.f, 0.f};
#pragma unroll
    for (int nt = 0; nt < 8; nt++){
      const int col = nt * 16 + r16;
      const float b1 = bg1v[col];
      const float w2 = wg2v[col];
#pragma unroll
      for (int r = 0; r < 4; r++){
        float gv = gacc[nt][r] + b1;
        gv = fmaxf(gv, 0.f);
        part[r] += gv * w2;
      }
    }
    const float bg2s = bg2v[0];
#pragma unroll
    for (int r = 0; r < 4; r++){
      float t = part[r];
      t += __shfl_xor(t, 1); t += __shfl_xor(t, 2);
      t += __shfl_xor(t, 4); t += __shfl_xor(t, 8);
      const float gu = 1.f / (1.f + __expf(-(t + bg2s)));
      const int rw = m0 + kg * 4 + r;
      if (r16 == 0){ gbuf[rw] = gu; outG[rowbase + rw] = gu; }
    }
  }
  __syncthreads();

  // ---- Phase 3: ATT(64x512) = W · u ; y = x + g*(att+bo); final-LN stats; y->Lb ----
  {
    const int ar = m0 + r16;
    short8 aw = *(const short8*)&Wl[ar * 32 + kg * 8];
    const unsigned short* ub = uTB + (size_t)bb * DD * 32;
    float psum[4] = {0.f,0.f,0.f,0.f}, psq[4] = {0.f,0.f,0.f,0.f};
    float gloc[4];
#pragma unroll
    for (int r = 0; r < 4; r++) gloc[r] = gbuf[m0 + kg * 4 + r];
    for (int nc = 0; nc < 4; nc++){
      f32x4 acc[8];
#pragma unroll
      for (int nt = 0; nt < 8; nt++){ f32x4 z = {0.f,0.f,0.f,0.f}; acc[nt] = z; }
#pragma unroll
      for (int nt = 0; nt < 8; nt++){
        const int n0 = nc * 128 + nt * 16;
        short8 bf = *(const short8*)&ub[(n0 + r16) * 32 + kg * 8];
        acc[nt] = __builtin_amdgcn_mfma_f32_16x16x32_bf16(aw, bf, acc[nt], 0, 0, 0);
      }
#pragma unroll
      for (int nt = 0; nt < 8; nt++){
        const int col = nc * 128 + nt * 16 + r16;
        const float boc = bov[col];
#pragma unroll
        for (int r = 0; r < 4; r++){
          const int rw = m0 + kg * 4 + r;
          const int idx = rw * DD + (col ^ ((rw & 7) << 3));
          float y = bf2f(Xb[idx]) + gloc[r] * (acc[nt][r] + boc);
          psum[r] += y; psq[r] += y * y;
          Lb[idx] = f2bf(y);
        }
      }
    }
#pragma unroll
    for (int r = 0; r < 4; r++){
      float s = psum[r], q = psq[r];
      s += __shfl_xor(s, 1); s += __shfl_xor(s, 2); s += __shfl_xor(s, 4); s += __shfl_xor(s, 8);
      q += __shfl_xor(q, 1); q += __shfl_xor(q, 2); q += __shfl_xor(q, 4); q += __shfl_xor(q, 8);
      const float mu = s * (1.f / DD);
      const float rs = rsqrtf(q * (1.f / DD) - mu * mu + 1e-5f);
      const int rw = m0 + kg * 4 + r;
      if (r16 == 0){ s2mu[rw] = mu; s2rs[rw] = rs; }
    }
  }
  __syncthreads();

  // ---- Phase 4: final LN + store fp32 ----
  {
    float lg[8], lb8[8];
    float4 g0 = *(const float4*)(lng + c0);
    float4 g1 = *(const float4*)(lng + c0 + 4);
    float4 b0 = *(const float4*)(lnb + c0);
    float4 b1 = *(const float4*)(lnb + c0 + 4);
    lg[0]=g0.x; lg[1]=g0.y; lg[2]=g0.z; lg[3]=g0.w;
    lg[4]=g1.x; lg[5]=g1.y; lg[6]=g1.z; lg[7]=g1.w;
    lb8[0]=b0.x; lb8[1]=b0.y; lb8[2]=b0.z; lb8[3]=b0.w;
    lb8[4]=b1.x; lb8[5]=b1.y; lb8[6]=b1.z; lb8[7]=b1.w;
    for (int rr = 0; rr < 16; rr++){
      const int r = m0 + rr;
      const float mu = s2mu[r], rs = s2rs[r];
      const int ci = c0 ^ ((r & 7) << 3);
      short8 yv = *(const short8*)&Lb[r * DD + ci];
      float o[8];
#pragma unroll
      for (int j = 0; j < 8; j++)
        o[j] = (bf2f((unsigned short)yv[j]) - mu) * rs * lg[j] + lb8[j];
      float* op = outF + (rowbase + r) * DD + c0;
      float4 o0; o0.x=o[0]; o0.y=o[1]; o0.z=o[2]; o0.w=o[3];
      float4 o1; o1.x=o[4]; o1.y=o[5]; o1.z=o[6]; o1.w=o[7];
      *(float4*)op = o0;
      *(float4*)(op + 4) = o1;
    }
  }
}

// ---------------- launch ----------------

extern "C" void kernel_launch(void* const* d_in, const int* in_sizes, int n_in,
                              void* d_out, int out_size, void* d_ws, size_t ws_size,
                              hipStream_t stream)
{
  const float* token = (const float*)d_in[0];
  const float* semb  = (const float*)d_in[1];
  const float* We    = (const float*)d_in[2];
  const float* be    = (const float*)d_in[3];
  const float* spos  = (const float*)d_in[4];
  const float* Wq    = (const float*)d_in[5];
  const float* bq    = (const float*)d_in[6];
  const float* Wk    = (const float*)d_in[7];
  const float* bk    = (const float*)d_in[8];
  const float* Wv    = (const float*)d_in[9];
  const float* bv    = (const float*)d_in[10];
  const float* Wo    = (const float*)d_in[11];
  const float* bo    = (const float*)d_in[12];
  const float* glng  = (const float*)d_in[13];
  const float* glnb  = (const float*)d_in[14];
  const float* Wg1   = (const float*)d_in[15];
  const float* bg1   = (const float*)d_in[16];
  const float* Wg2   = (const float*)d_in[17];
  const float* bg2   = (const float*)d_in[18];
  const float* lng   = (const float*)d_in[19];
  const float* lnb   = (const float*)d_in[20];

  char* ws = (char*)d_ws;
  float* spk            = (float*)(ws + 0);
  float* kb             = (float*)(ws + 65536);
  float* vb             = (float*)(ws + 131072);
  unsigned short* mB    = (unsigned short*)(ws + 196608);
  unsigned short* uTB   = (unsigned short*)(ws + 458752);
  float* cArr           = (float*)(ws + 720896);
  unsigned short* wg1B  = (unsigned short*)(ws + 721920);

  float* outF  = (float*)d_out;
  float* outAW = outF + (size_t)NB * TN * DD;
  float* outG  = outAW + (size_t)NB * TN * 4;

  prep_spk<<<dim3(64), dim3(256), 0, stream>>>(semb, We, be, spos, spk);
  prep_kv<<<dim3(64), dim3(256), 0, stream>>>(spk, Wk, bk, Wv, bv, kb, vb);
  prep_mu<<<dim3(1281), dim3(256), 0, stream>>>(kb, vb, Wq, bq, Wo, Wg1, mB, uTB, cArr, wg1B);
  fused_main<<<dim3(NB * TN / TT), dim3(256), 0, stream>>>(
      token, glng, glnb, bg1, Wg2, bg2, bo, lng, lnb,
      mB, uTB, cArr, wg1B, outF, outAW, outG);
}

// Round 2
// 105.675 us; speedup vs baseline: 1.4046x; 1.4046x over previous
//
#include <hip/hip_runtime.h>
#include <hip/hip_bf16.h>
#include <stdint.h>

typedef __attribute__((ext_vector_type(8))) short short8;
typedef __attribute__((ext_vector_type(4))) short short4v;
typedef __attribute__((ext_vector_type(4))) float f32x4;

#define DD 512
#define TT 16   // tokens per block (1 wave)
#define TN 4096 // T
#define NB 8    // B

__device__ __forceinline__ unsigned short f2bf(float f){
  uint32_t u = __float_as_uint(f);
  u += 0x7FFFu + ((u >> 16) & 1u);
  return (unsigned short)(u >> 16);
}
__device__ __forceinline__ float bf2f(unsigned short h){
  return __uint_as_float(((uint32_t)h) << 16);
}

// ---------------- prep kernels (quad-split dots) ----------------

// spk[b][od] = relu(se[b]·We[od] + be[od]) + spos[od]; 16384 outputs x 4 threads
__global__ void prep_spk(const float* __restrict__ se, const float* __restrict__ We,
                         const float* __restrict__ be, const float* __restrict__ spos,
                         float* __restrict__ spk){
  int idx = blockIdx.x * 256 + threadIdx.x;   // 65536
  int sub = idx & 3; int out = idx >> 2;
  int b = out & 7, od = out >> 3;
  const float* wr = We + (size_t)od * DD + sub * 4;
  const float* sb = se + b * DD + sub * 4;
  float acc = 0.f;
#pragma unroll 8
  for (int i = 0; i < 32; i++){
    float4 w = *(const float4*)(wr + i * 16);
    float4 x = *(const float4*)(sb + i * 16);
    acc += w.x * x.x + w.y * x.y + w.z * x.z + w.w * x.w;
  }
  acc += __shfl_xor(acc, 1); acc += __shfl_xor(acc, 2);
  if (sub == 0) spk[b * 2048 + od] = fmaxf(acc + be[od], 0.f) + spos[od];
}

// kb/vb[(b*4+s)*512+hd]; 16384 outputs x 4 threads
__global__ void prep_kv(const float* __restrict__ spk, const float* __restrict__ Wk,
                        const float* __restrict__ bk, const float* __restrict__ Wv,
                        const float* __restrict__ bv, float* __restrict__ kb,
                        float* __restrict__ vb){
  int idx = blockIdx.x * 256 + threadIdx.x;   // 65536
  int sub = idx & 3; int out = idx >> 2;
  int hd = out >> 5; int r = out & 31; int b = r >> 2, s = r & 3;
  const float* sp  = spk + (b * 4 + s) * DD + sub * 4;
  const float* wkr = Wk + (size_t)hd * DD + sub * 4;
  const float* wvr = Wv + (size_t)hd * DD + sub * 4;
  float ak = 0.f, av = 0.f;
#pragma unroll 8
  for (int i = 0; i < 32; i++){
    float4 x  = *(const float4*)(sp + i * 16);
    float4 wk = *(const float4*)(wkr + i * 16);
    float4 wv = *(const float4*)(wvr + i * 16);
    ak += x.x * wk.x + x.y * wk.y + x.z * wk.z + x.w * wk.w;
    av += x.x * wv.x + x.y * wv.y + x.z * wv.z + x.w * wv.w;
  }
  ak += __shfl_xor(ak, 1); ak += __shfl_xor(ak, 2);
  av += __shfl_xor(av, 1); av += __shfl_xor(av, 2);
  if (sub == 0){
    kb[(b * 4 + s) * DD + hd] = ak + bk[hd];
    vb[(b * 4 + s) * DD + hd] = av + bv[hd];
  }
}

// mB, uT, wg1B (gamma-folded), cArr, e1/e2
__global__ void prep_mu(const float* __restrict__ kb, const float* __restrict__ vb,
                        const float* __restrict__ Wq, const float* __restrict__ bq,
                        const float* __restrict__ Wo, const float* __restrict__ Wg1,
                        const float* __restrict__ glng, const float* __restrict__ glnb,
                        const float* __restrict__ bg1,
                        unsigned short* __restrict__ mB, unsigned short* __restrict__ uT,
                        float* __restrict__ cArr, unsigned short* __restrict__ wg1B,
                        float* __restrict__ e1, float* __restrict__ e2){
  int idx = blockIdx.x * 256 + threadIdx.x;     // 328064 total
  if (idx < 131072){
    int d = idx & 511; int j = (idx >> 9) & 31; int b = idx >> 14;
    int h = j >> 2, s = j & 3;
    const float* kr = kb + (b * 4 + s) * DD + h * 64;
    const float* wq = Wq + (size_t)(h * 64) * DD + d;
    float acc = 0.f;
#pragma unroll 16
    for (int dh = 0; dh < 64; dh++) acc += wq[(size_t)dh * DD] * kr[dh];
    mB[idx] = f2bf(acc);
  } else if (idx < 262144){
    int t = idx - 131072;
    int j = t & 31; int d = (t >> 5) & 511; int b = t >> 14;
    int h = j >> 2, s = j & 3;
    const float* vr = vb + (b * 4 + s) * DD + h * 64;
    const float* wo = Wo + (size_t)d * DD + h * 64;
    float acc = 0.f;
#pragma unroll 8
    for (int dh = 0; dh < 64; dh += 4){
      float4 v4 = *(const float4*)(vr + dh);
      float4 w4 = *(const float4*)(wo + dh);
      acc += v4.x * w4.x + v4.y * w4.y + v4.z * w4.z + v4.w * w4.w;
    }
    uT[b * 16384 + d * 32 + j] = f2bf(acc);
  } else if (idx < 327680){
    int t = idx - 262144;
    wg1B[t] = f2bf(Wg1[t] * glng[t & 511]);
  } else if (idx < 327936){
    int t = idx - 327680; int j = t & 31, b = t >> 5;
    int h = j >> 2, s = j & 3;
    const float* kr = kb + (b * 4 + s) * DD + h * 64;
    const float* bqp = bq + h * 64;
    float acc = 0.f;
    for (int dh = 0; dh < 64; dh++) acc += bqp[dh] * kr[dh];
    cArr[b * 32 + j] = acc;
  } else if (idx < 328064){
    int col = idx - 327936;
    const float* wr = Wg1 + (size_t)col * DD;
    float a1 = 0.f, a2 = 0.f;
    for (int d = 0; d < DD; d += 4){
      float4 w  = *(const float4*)(wr + d);
      float4 gm = *(const float4*)(glng + d);
      float4 bt = *(const float4*)(glnb + d);
      a1 += w.x * gm.x + w.y * gm.y + w.z * gm.z + w.w * gm.w;
      a2 += w.x * bt.x + w.y * bt.y + w.z * bt.z + w.w * bt.w;
    }
    e1[col] = a1; e2[col] = a2 + bg1[col];
  }
}

// ---------------- main fused kernel: 1 wave per block, 16 tokens ----------------

__global__ __launch_bounds__(64) void fused_main(
    const float* __restrict__ xin,
    const float* __restrict__ e1v, const float* __restrict__ e2v,
    const float* __restrict__ wg2v, const float* __restrict__ bg2v,
    const float* __restrict__ bov,  const float* __restrict__ lng, const float* __restrict__ lnb,
    const unsigned short* __restrict__ mB,
    const unsigned short* __restrict__ uTB,
    const float* __restrict__ cArr,
    const unsigned short* __restrict__ wg1B,
    float* __restrict__ outF, float* __restrict__ outAW, float* __restrict__ outG)
{
  __shared__ __align__(16) unsigned short Xb[TT * DD];   // 16 KB: x bf16, later y bf16
  __shared__ __align__(16) unsigned short Wl[TT * 32];   // 1 KB softmax weights
  __shared__ float smu[TT], srs[TT], s2mu[TT], s2rs[TT];

  const int lane = threadIdx.x;
  const int r16 = lane & 15;
  const int kg  = lane >> 4;
  const int bb  = blockIdx.x >> 8;            // batch
  const int t0  = (blockIdx.x & 255) << 4;    // token tile base
  const size_t rowbase = (size_t)bb * TN + t0;

  // ---- Phase 0: load X (fp32), LN stats, store bf16 swizzled ----
  {
#pragma unroll
    for (int g = 0; g < 4; g++){
      const int r = g * 4 + kg;
      const float* rp = xin + (rowbase + r) * DD;
      const int swz = (r & 7) << 3;
      float s = 0.f, q = 0.f;
#pragma unroll
      for (int cc = 0; cc < 4; cc++){
        const int c = cc * 128 + r16 * 8;
        float4 v0 = *(const float4*)(rp + c);
        float4 v1 = *(const float4*)(rp + c + 4);
        float xv[8] = {v0.x, v0.y, v0.z, v0.w, v1.x, v1.y, v1.z, v1.w};
        short8 pk;
#pragma unroll
        for (int j = 0; j < 8; j++){
          s += xv[j]; q += xv[j] * xv[j];
          pk[j] = (short)f2bf(xv[j]);
        }
        *(short8*)&Xb[r * DD + (c ^ swz)] = pk;
      }
      s += __shfl_xor(s, 1); s += __shfl_xor(s, 2); s += __shfl_xor(s, 4); s += __shfl_xor(s, 8);
      q += __shfl_xor(q, 1); q += __shfl_xor(q, 2); q += __shfl_xor(q, 4); q += __shfl_xor(q, 8);
      const float mu = s * (1.f / DD);
      const float rs = rsqrtf(q * (1.f / DD) - mu * mu + 1e-5f);
      if (r16 == 0){ smu[r] = mu; srs[r] = rs; }
    }
  }
  __syncthreads();

  // ---- Phase 1+2 merged: scores + gate GEMM off the same A-fragments ----
  f32x4 sa0 = {0.f,0.f,0.f,0.f}, sa1 = {0.f,0.f,0.f,0.f};
  f32x4 gacc[8];
#pragma unroll
  for (int nt = 0; nt < 8; nt++){ f32x4 z = {0.f,0.f,0.f,0.f}; gacc[nt] = z; }
  {
    const unsigned short* mb = mB + (size_t)bb * 32 * DD;
    const int swz = (r16 & 7) << 3;
#pragma unroll
    for (int kt = 0; kt < 16; kt++){
      const int kc = kt * 32 + kg * 8;
      short8 a  = *(const short8*)&Xb[r16 * DD + (kc ^ swz)];
      short8 b0 = *(const short8*)&mb[r16 * DD + kc];
      short8 b1 = *(const short8*)&mb[(r16 + 16) * DD + kc];
      sa0 = __builtin_amdgcn_mfma_f32_16x16x32_bf16(a, b0, sa0, 0, 0, 0);
      sa1 = __builtin_amdgcn_mfma_f32_16x16x32_bf16(a, b1, sa1, 0, 0, 0);
#pragma unroll
      for (int nt = 0; nt < 8; nt++){
        short8 wf = *(const short8*)&wg1B[(size_t)(nt * 16 + r16) * DD + kc];
        gacc[nt] = __builtin_amdgcn_mfma_f32_16x16x32_bf16(wf, a, gacc[nt], 0, 0, 0);
      }
    }
  }

  // softmax epilogue: thread owns tokens kg*4+r, j = r16
  {
    const float c0v = cArr[bb * 32 + r16];
    const float c1v = cArr[bb * 32 + r16 + 16];
#pragma unroll
    for (int r = 0; r < 4; r++){
      float s0 = (sa0[r] + c0v) * 0.125f;
      float s1 = (sa1[r] + c1v) * 0.125f;
      float mx0 = fmaxf(s0, __shfl_xor(s0, 1)); mx0 = fmaxf(mx0, __shfl_xor(mx0, 2));
      float mx1 = fmaxf(s1, __shfl_xor(s1, 1)); mx1 = fmaxf(mx1, __shfl_xor(mx1, 2));
      float e0 = __expf(s0 - mx0), e1x = __expf(s1 - mx1);
      float d0 = e0;  d0 += __shfl_xor(d0, 1); d0 += __shfl_xor(d0, 2);
      float d1 = e1x; d1 += __shfl_xor(d1, 1); d1 += __shfl_xor(d1, 2);
      float w0 = e0 / d0, w1 = e1x / d1;
      float t = w0 + w1; t += __shfl_xor(t, 4); t += __shfl_xor(t, 8); t *= 0.125f;
      const int rw = kg * 4 + r;
      if ((lane & 12) == 0) outAW[(rowbase + rw) * 4 + (lane & 3)] = t;
      Wl[rw * 32 + r16]      = f2bf(w0);
      Wl[rw * 32 + r16 + 16] = f2bf(w1);
    }
  }

  // gate epilogue: thread owns token r16, gate cols nt*16+kg*4+r
  float g_reg;
  {
    const float muv = smu[r16];
    const float rsv = srs[r16];
    float part = 0.f;
#pragma unroll
    for (int nt = 0; nt < 8; nt++){
      const int c4 = nt * 16 + kg * 4;
      float4 e1c = *(const float4*)(e1v + c4);
      float4 e2c = *(const float4*)(e2v + c4);
      float4 w2c = *(const float4*)(wg2v + c4);
      float e1a[4] = {e1c.x, e1c.y, e1c.z, e1c.w};
      float e2a[4] = {e2c.x, e2c.y, e2c.z, e2c.w};
      float w2a[4] = {w2c.x, w2c.y, w2c.z, w2c.w};
#pragma unroll
      for (int r = 0; r < 4; r++){
        float gv = rsv * (gacc[nt][r] - muv * e1a[r]) + e2a[r];
        gv = fmaxf(gv, 0.f);
        part += gv * w2a[r];
      }
    }
    part += __shfl_xor(part, 16); part += __shfl_xor(part, 32);
    g_reg = 1.f / (1.f + __expf(-(part + bg2v[0])));
    if (kg == 0) outG[rowbase + r16] = g_reg;
  }
  __syncthreads();

  // ---- Phase 3: ATT = u·W (swapped: thread owns token r16) ; y in-place in Xb ----
  {
    const int tok = r16;
    short8 aw = *(const short8*)&Wl[tok * 32 + kg * 8];
    const unsigned short* ub = uTB + (size_t)bb * DD * 32;
    const int swzT = (tok & 7) << 3;
    float psum = 0.f, psq = 0.f;
    for (int nc = 0; nc < 4; nc++){
      f32x4 acc[8];
#pragma unroll
      for (int nt = 0; nt < 8; nt++){ f32x4 z = {0.f,0.f,0.f,0.f}; acc[nt] = z; }
#pragma unroll
      for (int nt = 0; nt < 8; nt++){
        const int n0 = nc * 128 + nt * 16;
        short8 uf = *(const short8*)&ub[(n0 + r16) * 32 + kg * 8];
        acc[nt] = __builtin_amdgcn_mfma_f32_16x16x32_bf16(uf, aw, acc[nt], 0, 0, 0);
      }
#pragma unroll
      for (int nt = 0; nt < 8; nt++){
        const int c4 = nc * 128 + nt * 16 + kg * 4;
        float4 bo4 = *(const float4*)(bov + c4);
        float boa[4] = {bo4.x, bo4.y, bo4.z, bo4.w};
        const int idx = tok * DD + (c4 ^ swzT);
        short4v xv = *(short4v*)&Xb[idx];
        short4v yv;
#pragma unroll
        for (int r = 0; r < 4; r++){
          float y = bf2f((unsigned short)xv[r]) + g_reg * (acc[nt][r] + boa[r]);
          psum += y; psq += y * y;
          yv[r] = (short)f2bf(y);
        }
        *(short4v*)&Xb[idx] = yv;
      }
    }
    psum += __shfl_xor(psum, 16); psum += __shfl_xor(psum, 32);
    psq  += __shfl_xor(psq, 16);  psq  += __shfl_xor(psq, 32);
    const float mu = psum * (1.f / DD);
    const float rs = rsqrtf(psq * (1.f / DD) - mu * mu + 1e-5f);
    if (kg == 0){ s2mu[tok] = mu; s2rs[tok] = rs; }
  }
  __syncthreads();

  // ---- Phase 4: final LN + fp32 store ----
  {
    const int c0 = lane << 3;
    float lg[8], lb8[8];
    {
      float4 g0 = *(const float4*)(lng + c0);
      float4 g1 = *(const float4*)(lng + c0 + 4);
      float4 b0 = *(const float4*)(lnb + c0);
      float4 b1 = *(const float4*)(lnb + c0 + 4);
      lg[0]=g0.x; lg[1]=g0.y; lg[2]=g0.z; lg[3]=g0.w;
      lg[4]=g1.x; lg[5]=g1.y; lg[6]=g1.z; lg[7]=g1.w;
      lb8[0]=b0.x; lb8[1]=b0.y; lb8[2]=b0.z; lb8[3]=b0.w;
      lb8[4]=b1.x; lb8[5]=b1.y; lb8[6]=b1.z; lb8[7]=b1.w;
    }
#pragma unroll
    for (int r = 0; r < TT; r++){
      const float mu = s2mu[r], rs = s2rs[r];
      const int ci = c0 ^ ((r & 7) << 3);
      short8 yv = *(const short8*)&Xb[r * DD + ci];
      float o[8];
#pragma unroll
      for (int j = 0; j < 8; j++)
        o[j] = (bf2f((unsigned short)yv[j]) - mu) * rs * lg[j] + lb8[j];
      float* op = outF + (rowbase + r) * DD + c0;
      float4 o0; o0.x=o[0]; o0.y=o[1]; o0.z=o[2]; o0.w=o[3];
      float4 o1; o1.x=o[4]; o1.y=o[5]; o1.z=o[6]; o1.w=o[7];
      *(float4*)op = o0;
      *(float4*)(op + 4) = o1;
    }
  }
}

// ---------------- launch ----------------

extern "C" void kernel_launch(void* const* d_in, const int* in_sizes, int n_in,
                              void* d_out, int out_size, void* d_ws, size_t ws_size,
                              hipStream_t stream)
{
  const float* token = (const float*)d_in[0];
  const float* semb  = (const float*)d_in[1];
  const float* We    = (const float*)d_in[2];
  const float* be    = (const float*)d_in[3];
  const float* spos  = (const float*)d_in[4];
  const float* Wq    = (const float*)d_in[5];
  const float* bq    = (const float*)d_in[6];
  const float* Wk    = (const float*)d_in[7];
  const float* bk    = (const float*)d_in[8];
  const float* Wv    = (const float*)d_in[9];
  const float* bv    = (const float*)d_in[10];
  const float* Wo    = (const float*)d_in[11];
  const float* bo    = (const float*)d_in[12];
  const float* glng  = (const float*)d_in[13];
  const float* glnb  = (const float*)d_in[14];
  const float* Wg1   = (const float*)d_in[15];
  const float* bg1   = (const float*)d_in[16];
  const float* Wg2   = (const float*)d_in[17];
  const float* bg2   = (const float*)d_in[18];
  const float* lng   = (const float*)d_in[19];
  const float* lnb   = (const float*)d_in[20];

  char* ws = (char*)d_ws;
  // e1/e2 overlap the spk region (spk dead after prep_kv; prep_mu writes e1/e2)
  float* e1             = (float*)(ws + 0);        // 512 B
  float* e2             = (float*)(ws + 512);      // 512 B
  float* spk            = (float*)(ws + 0);        // 64 KB (consumed before e1/e2 written)
  float* kb             = (float*)(ws + 65536);
  float* vb             = (float*)(ws + 131072);
  unsigned short* mB    = (unsigned short*)(ws + 196608);
  unsigned short* uTB   = (unsigned short*)(ws + 458752);
  float* cArr           = (float*)(ws + 720896);
  unsigned short* wg1B  = (unsigned short*)(ws + 721920);

  float* outF  = (float*)d_out;
  float* outAW = outF + (size_t)NB * TN * DD;
  float* outG  = outAW + (size_t)NB * TN * 4;

  prep_spk<<<dim3(256), dim3(256), 0, stream>>>(semb, We, be, spos, spk);
  prep_kv<<<dim3(256), dim3(256), 0, stream>>>(spk, Wk, bk, Wv, bv, kb, vb);
  prep_mu<<<dim3(1282), dim3(256), 0, stream>>>(kb, vb, Wq, bq, Wo, Wg1, glng, glnb, bg1,
                                                mB, uTB, cArr, wg1B, e1, e2);
  fused_main<<<dim3(NB * TN / TT), dim3(64), 0, stream>>>(
      token, e1, e2, Wg2, bg2, bo, lng, lnb,
      mB, uTB, cArr, wg1B, outF, outAW, outG);
}